// Round 8
// baseline (206.353 us; speedup 1.0000x reference)
//
#include <hip/hip_runtime.h>
#include <hip/hip_bf16.h>
#include <math.h>

#define NHEADS 16
#define DHEAD  64
#define CHDIM  80
#define RQn    6
#define RKn    2
#define RVn    2
#define BB     2
#define TT     2048
#define DDim   1024
#define NQK    800   // 480 + 320 combined projection rows

using frag16 = __attribute__((ext_vector_type(8))) short;   // 8 bf16 (4 VGPR)
using f32x4  = __attribute__((ext_vector_type(4))) float;   // 4 fp32 acc
using f32x16 = __attribute__((ext_vector_type(16))) float;  // 32x32 acc

#define AS1(p) ((const __attribute__((address_space(1))) unsigned int*)(p))
#define AS3(p) ((__attribute__((address_space(3))) unsigned int*)(p))

static __device__ __forceinline__ unsigned short bf16_bits(float f) {
    __hip_bfloat16 h = __float2bfloat16(f);
    return *(unsigned short*)&h;
}
static __device__ __forceinline__ unsigned int pk2(float a, float b) {
    return ((unsigned int)bf16_bits(b) << 16) | (unsigned int)bf16_bits(a);
}
static __device__ __forceinline__ uint4 pk8(const float4& a, const float4& b) {
    uint4 u;
    u.x = pk2(a.x, a.y); u.y = pk2(a.z, a.w);
    u.z = pk2(b.x, b.y); u.w = pk2(b.z, b.w);
    return u;
}

// ============ GEMM1: abqkv[4096][800] = x_f32 @ [W_abq; W_abkv]_f32^T ========
// fp32->bf16 conversion fused into staging (VGPR prefetch + ds_write, XOR
// chunk-swizzled LDS layout identical to the old global_load_lds layout).
__global__ __launch_bounds__(256) void gemm_proj(
    const float* __restrict__ A, const float* __restrict__ Wq,
    const float* __restrict__ Wk, float* __restrict__ C)
{
    const int M = 4096, N = NQK, K = 1024;
    __shared__ __hip_bfloat16 Asl[128 * 64];
    __shared__ __hip_bfloat16 Bsl[128 * 64];
    const int tid = threadIdx.x;
    const int w = tid >> 6, lane = tid & 63;
    const int l16 = lane & 15, quad = lane >> 4;
    const int wr = w >> 1, wc = w & 1;
    const int bm = blockIdx.y * 128, bn = blockIdx.x * 128;

    const float* aP[4]; const float* bP[4]; int ldsOff[4];
    #pragma unroll
    for (int j = 0; j < 4; j++) {
        int L = (w * 4 + j) * 64 + lane;
        int r = L >> 3;
        int c8 = (L & 7) ^ (r & 7);
        aP[j] = A + (size_t)(bm + r) * K + c8 * 8;
        int rb = bn + r; if (rb >= N) rb = N - 1;
        bP[j] = (rb < 480) ? (Wq + (size_t)rb * K + c8 * 8)
                           : (Wk + (size_t)(rb - 480) * K + c8 * 8);
        ldsOff[j] = (w * 4 + j) * 512 + lane * 8;
    }

    f32x4 acc[4][4];
    #pragma unroll
    for (int mt = 0; mt < 4; mt++)
        #pragma unroll
        for (int nt = 0; nt < 4; nt++)
            acc[mt][nt] = (f32x4){0.f, 0.f, 0.f, 0.f};

    float4 av[4][2], bv[4][2];
    #pragma unroll
    for (int j = 0; j < 4; j++) {
        av[j][0] = *(const float4*)(aP[j]);     av[j][1] = *(const float4*)(aP[j] + 4);
        bv[j][0] = *(const float4*)(bP[j]);     bv[j][1] = *(const float4*)(bP[j] + 4);
    }

    const int nK = K >> 6;
    for (int kk = 0; kk < nK; kk++) {
        __syncthreads();   // chunk kk-1 LDS reads complete
        #pragma unroll
        for (int j = 0; j < 4; j++) {
            *(uint4*)&Asl[ldsOff[j]] = pk8(av[j][0], av[j][1]);
            *(uint4*)&Bsl[ldsOff[j]] = pk8(bv[j][0], bv[j][1]);
        }
        __syncthreads();   // ds_writes visible
        if (kk + 1 < nK) {
            const int k1 = (kk + 1) * 64;
            #pragma unroll
            for (int j = 0; j < 4; j++) {
                av[j][0] = *(const float4*)(aP[j] + k1);
                av[j][1] = *(const float4*)(aP[j] + k1 + 4);
                bv[j][0] = *(const float4*)(bP[j] + k1);
                bv[j][1] = *(const float4*)(bP[j] + k1 + 4);
            }
        }
        #pragma unroll
        for (int ks = 0; ks < 2; ks++) {
            frag16 af[4], bf[4];
            #pragma unroll
            for (int mt = 0; mt < 4; mt++) {
                int r = wr * 64 + mt * 16 + l16;
                af[mt] = *(const frag16*)&Asl[r * 64 + (((ks * 4 + quad) ^ (r & 7)) * 8)];
            }
            #pragma unroll
            for (int nt = 0; nt < 4; nt++) {
                int r = wc * 64 + nt * 16 + l16;
                bf[nt] = *(const frag16*)&Bsl[r * 64 + (((ks * 4 + quad) ^ (r & 7)) * 8)];
            }
            #pragma unroll
            for (int mt = 0; mt < 4; mt++)
                #pragma unroll
                for (int nt = 0; nt < 4; nt++)
                    acc[mt][nt] = __builtin_amdgcn_mfma_f32_16x16x32_bf16(af[mt], bf[nt], acc[mt][nt], 0, 0, 0);
        }
    }
    #pragma unroll
    for (int mt = 0; mt < 4; mt++) {
        #pragma unroll
        for (int reg = 0; reg < 4; reg++) {
            int row = bm + wr * 64 + mt * 16 + quad * 4 + reg;
            #pragma unroll
            for (int nt = 0; nt < 4; nt++) {
                int col = bn + wc * 64 + nt * 16 + l16;
                if (col < N) C[(size_t)row * N + col] = acc[mt][nt][reg];
            }
        }
    }
}

// ============ GEMM2: out[4096][1024] = y @ W_o_f32^T, combine fused =========
// A rows of a block are one qt tile: lo (qt<8) -> yb bf16; hi -> combine
// Op0+Op1 scaled by 1/(l0+l1) during staging (chunk kk == head, slot uniform).
// B = W_o fp32 converted in staging.
__global__ __launch_bounds__(256) void gemm_out(
    const __hip_bfloat16* __restrict__ Y, const float* __restrict__ Op,
    const float* __restrict__ Lp, const float* __restrict__ Wo,
    float* __restrict__ C)
{
    const int N = 1024, K = 1024;
    __shared__ __hip_bfloat16 Asl[128 * 64];
    __shared__ __hip_bfloat16 Bsl[128 * 64];
    const int tid = threadIdx.x;
    const int w = tid >> 6, lane = tid & 63;
    const int l16 = lane & 15, quad = lane >> 4;
    const int wr = w >> 1, wc = w & 1;
    const int bm = blockIdx.y * 128, bn = blockIdx.x * 128;
    const int bb = bm >> 11;                 // batch
    const int qt = (bm & 2047) >> 7;
    const bool hiB = (qt >= 8);
    const int qthalf = 15 - qt;

    int rA[4], c8A[4], ldsOff[4];
    const float* bP[4];
    #pragma unroll
    for (int j = 0; j < 4; j++) {
        int L = (w * 4 + j) * 64 + lane;
        int r = L >> 3;
        int c8 = (L & 7) ^ (r & 7);
        rA[j] = r; c8A[j] = c8;
        bP[j] = Wo + (size_t)(bn + r) * K + c8 * 8;
        ldsOff[j] = (w * 4 + j) * 512 + lane * 8;
    }

    f32x4 acc[4][4];
    #pragma unroll
    for (int mt = 0; mt < 4; mt++)
        #pragma unroll
        for (int nt = 0; nt < 4; nt++)
            acc[mt][nt] = (f32x4){0.f, 0.f, 0.f, 0.f};

    float4 bv[4][2];
    // A staging regs: lo uses uv[]; hi uses a0v/a1v + lv
    uint4 uv[4];
    float4 a0v[4][2], a1v[4][2];
    float l0v[4], l1v[4];

    // ---- prefetch chunk 0 ----
    #pragma unroll
    for (int j = 0; j < 4; j++) {
        bv[j][0] = *(const float4*)(bP[j]);
        bv[j][1] = *(const float4*)(bP[j] + 4);
    }
    if (hiB) {
        const int slot0 = (bb * 16 + 0) * 8 + qthalf;
        #pragma unroll
        for (int j = 0; j < 4; j++) {
            const float* p0 = Op + (size_t)slot0 * 8192 + rA[j] * 64 + c8A[j] * 8;
            a0v[j][0] = *(const float4*)(p0);           a0v[j][1] = *(const float4*)(p0 + 4);
            a1v[j][0] = *(const float4*)(p0 + 2097152); a1v[j][1] = *(const float4*)(p0 + 2097152 + 4);
            l0v[j] = Lp[slot0 * 128 + rA[j]];
            l1v[j] = Lp[32768 + slot0 * 128 + rA[j]];
        }
    } else {
        #pragma unroll
        for (int j = 0; j < 4; j++)
            uv[j] = *(const uint4*)&Y[(size_t)(bm + rA[j]) * K + c8A[j] * 8];
    }

    const int nK = K >> 6;
    for (int kk = 0; kk < nK; kk++) {
        __syncthreads();
        #pragma unroll
        for (int j = 0; j < 4; j++)
            *(uint4*)&Bsl[ldsOff[j]] = pk8(bv[j][0], bv[j][1]);
        if (hiB) {
            #pragma unroll
            for (int j = 0; j < 4; j++) {
                float inv = 1.0f / (l0v[j] + l1v[j]);
                float4 s0, s1;
                s0.x = (a0v[j][0].x + a1v[j][0].x) * inv;
                s0.y = (a0v[j][0].y + a1v[j][0].y) * inv;
                s0.z = (a0v[j][0].z + a1v[j][0].z) * inv;
                s0.w = (a0v[j][0].w + a1v[j][0].w) * inv;
                s1.x = (a0v[j][1].x + a1v[j][1].x) * inv;
                s1.y = (a0v[j][1].y + a1v[j][1].y) * inv;
                s1.z = (a0v[j][1].z + a1v[j][1].z) * inv;
                s1.w = (a0v[j][1].w + a1v[j][1].w) * inv;
                *(uint4*)&Asl[ldsOff[j]] = pk8(s0, s1);
            }
        } else {
            #pragma unroll
            for (int j = 0; j < 4; j++)
                *(uint4*)&Asl[ldsOff[j]] = uv[j];
        }
        __syncthreads();
        if (kk + 1 < nK) {
            const int k1 = (kk + 1) * 64;
            #pragma unroll
            for (int j = 0; j < 4; j++) {
                bv[j][0] = *(const float4*)(bP[j] + k1);
                bv[j][1] = *(const float4*)(bP[j] + k1 + 4);
            }
            if (hiB) {
                const int slot = (bb * 16 + (kk + 1)) * 8 + qthalf;
                #pragma unroll
                for (int j = 0; j < 4; j++) {
                    const float* p0 = Op + (size_t)slot * 8192 + rA[j] * 64 + c8A[j] * 8;
                    a0v[j][0] = *(const float4*)(p0);           a0v[j][1] = *(const float4*)(p0 + 4);
                    a1v[j][0] = *(const float4*)(p0 + 2097152); a1v[j][1] = *(const float4*)(p0 + 2097152 + 4);
                    l0v[j] = Lp[slot * 128 + rA[j]];
                    l1v[j] = Lp[32768 + slot * 128 + rA[j]];
                }
            } else {
                #pragma unroll
                for (int j = 0; j < 4; j++)
                    uv[j] = *(const uint4*)&Y[(size_t)(bm + rA[j]) * K + k1 + c8A[j] * 8];
            }
        }
        #pragma unroll
        for (int ks = 0; ks < 2; ks++) {
            frag16 af[4], bf[4];
            #pragma unroll
            for (int mt = 0; mt < 4; mt++) {
                int r = wr * 64 + mt * 16 + l16;
                af[mt] = *(const frag16*)&Asl[r * 64 + (((ks * 4 + quad) ^ (r & 7)) * 8)];
            }
            #pragma unroll
            for (int nt = 0; nt < 4; nt++) {
                int r = wc * 64 + nt * 16 + l16;
                bf[nt] = *(const frag16*)&Bsl[r * 64 + (((ks * 4 + quad) ^ (r & 7)) * 8)];
            }
            #pragma unroll
            for (int mt = 0; mt < 4; mt++)
                #pragma unroll
                for (int nt = 0; nt < 4; nt++)
                    acc[mt][nt] = __builtin_amdgcn_mfma_f32_16x16x32_bf16(af[mt], bf[nt], acc[mt][nt], 0, 0, 0);
        }
    }
    #pragma unroll
    for (int mt = 0; mt < 4; mt++) {
        #pragma unroll
        for (int reg = 0; reg < 4; reg++) {
            int row = bm + wr * 64 + mt * 16 + quad * 4 + reg;
            #pragma unroll
            for (int nt = 0; nt < 4; nt++) {
                int col = bn + wc * 64 + nt * 16 + l16;
                C[(size_t)row * N + col] = acc[mt][nt][reg];
            }
        }
    }
}

// ---------------- RoPE + rank contraction, 4 tokens/block ----------
__global__ __launch_bounds__(256) void qkv_kernel(
    const float* __restrict__ ab,
    __hip_bfloat16* __restrict__ q, __hip_bfloat16* __restrict__ k,
    __hip_bfloat16* __restrict__ vT)
{
    const int tok0 = blockIdx.x * 4;
    const int w = threadIdx.x >> 6;
    const int d = threadIdx.x & 63;
    const int token = tok0 + w;
    const int b = token / TT;
    const int t = token % TT;
    __shared__ float sq[4][RQn * CHDIM];
    __shared__ float skv[4][(RKn + RVn) * CHDIM];
    __shared__ __align__(8) __hip_bfloat16 vbuf[NHEADS][DHEAD][4];
    const float* aq  = ab + (size_t)token * NQK;
    const float* akv = aq + 480;
    for (int i = d; i < RQn * CHDIM; i += 64) sq[w][i] = aq[i];
    for (int i = d; i < (RKn + RVn) * CHDIM; i += 64) skv[w][i] = akv[i];
    const int i32 = d & 31;
    float inv_freq = powf(10000.0f, -(float)i32 / 32.0f);
    float fr = (float)t * inv_freq;
    float c = cosf(fr), s = sinf(fr);
    float rot[4];
    #pragma unroll
    for (int r = 0; r < 4; r++) {
        float x1 = skv[w][r * CHDIM + NHEADS + i32];
        float x2 = skv[w][r * CHDIM + NHEADS + 32 + i32];
        rot[r] = (d < 32) ? (x1 * c + x2 * s) : (-x1 * s + x2 * c);
    }
    float bqv[RQn];
    #pragma unroll
    for (int r = 0; r < RQn; r++) bqv[r] = sq[w][r * CHDIM + NHEADS + d];
    #pragma unroll
    for (int h = 0; h < NHEADS; h++) {
        float accq = 0.0f;
        #pragma unroll
        for (int r = 0; r < RQn; r++)
            accq += sq[w][r * CHDIM + h] * bqv[r];
        q[((size_t)(b * NHEADS + h) * TT + t) * DHEAD + d] = __float2bfloat16(accq * (0.125f / 6.0f));
        float acck = 0.0f, accv = 0.0f;
        #pragma unroll
        for (int r = 0; r < RKn; r++)
            acck += skv[w][r * CHDIM + h] * rot[r];
        #pragma unroll
        for (int r = 0; r < RVn; r++)
            accv += skv[w][(RKn + r) * CHDIM + h] * rot[RKn + r];
        k[((size_t)(b * NHEADS + h) * TT + t) * DHEAD + d] = __float2bfloat16(acck * 0.5f);
        vbuf[h][d][w] = __float2bfloat16(accv * 0.5f);
    }
    __syncthreads();
    const int t0 = tok0 % TT;
    const int b0 = tok0 / TT;
    for (int row = threadIdx.x; row < NHEADS * DHEAD; row += 256) {
        int h = row >> 6, dd = row & 63;
        *(uint2*)&vT[((size_t)(b0 * NHEADS + h) * DHEAD + dd) * TT + t0] =
            *(const uint2*)&vbuf[h][dd][0];
    }
}

// ---------------- one attention tile: S^T = K·Q^T, P=exp, O^T += V^T·P^T ----
static __device__ __forceinline__ void attn_tile(
    const __hip_bfloat16* __restrict__ Kc, const __hip_bfloat16* __restrict__ Vc,
    const frag16 qB[4], f32x16& O0, f32x16& O1, float& lpart,
    const int l31, const int hi, const int xi, const int paddr,
    const bool domask, const int kb0, const int qlane)
{
    f32x16 ST0 = {}, ST1 = {};
    #pragma unroll
    for (int kt4 = 0; kt4 < 4; kt4++) {
        int c8 = kt4 * 2 + hi;
        frag16 kf0 = *(const frag16*)&Kc[l31 * 64 + ((c8 ^ xi) * 8)];
        frag16 kf1 = *(const frag16*)&Kc[(32 + l31) * 64 + ((c8 ^ xi) * 8)];
        ST0 = __builtin_amdgcn_mfma_f32_32x32x16_bf16(kf0, qB[kt4], ST0, 0, 0, 0);
        ST1 = __builtin_amdgcn_mfma_f32_32x32x16_bf16(kf1, qB[kt4], ST1, 0, 0, 0);
    }
    float* s0 = (float*)&ST0;
    float* s1 = (float*)&ST1;
    if (domask) {
        int kbq = kb0 + 4 * hi;
        #pragma unroll
        for (int reg = 0; reg < 16; reg++) {
            int rowc = (reg & 3) + 8 * (reg >> 2);
            if (kbq + rowc > qlane)      s0[reg] = -1e30f;
            if (kbq + 32 + rowc > qlane) s1[reg] = -1e30f;
        }
    }
    #pragma unroll
    for (int reg = 0; reg < 16; reg++) {
        float p0 = __expf(s0[reg]);
        float p1 = __expf(s1[reg]);
        s0[reg] = p0; s1[reg] = p1;
        lpart += p0 + p1;
    }
    frag16 Pf[4];
    #pragma unroll
    for (int k2 = 0; k2 < 4; k2++) {
        const float* sF = (k2 >= 2) ? s1 : s0;
        const int bs = 8 * (k2 & 1);
        unsigned int u0a = pk2(sF[bs + 0], sF[bs + 1]);
        unsigned int u0b = pk2(sF[bs + 2], sF[bs + 3]);
        unsigned int u1a = pk2(sF[bs + 4], sF[bs + 5]);
        unsigned int u1b = pk2(sF[bs + 6], sF[bs + 7]);
        unsigned int r0a = (unsigned int)__builtin_amdgcn_ds_bpermute(paddr, (int)u0a);
        unsigned int r0b = (unsigned int)__builtin_amdgcn_ds_bpermute(paddr, (int)u0b);
        unsigned int r1a = (unsigned int)__builtin_amdgcn_ds_bpermute(paddr, (int)u1a);
        unsigned int r1b = (unsigned int)__builtin_amdgcn_ds_bpermute(paddr, (int)u1b);
        union { frag16 f; unsigned int u[4]; } pf;
        pf.u[0] = hi ? r1a : u0a;
        pf.u[1] = hi ? r1b : u0b;
        pf.u[2] = hi ? u1a : r0a;
        pf.u[3] = hi ? u1b : r0b;
        Pf[k2] = pf.f;
    }
    #pragma unroll
    for (int k2 = 0; k2 < 4; k2++) {
        int c8 = k2 * 2 + hi;
        frag16 vf0 = *(const frag16*)&Vc[l31 * 64 + ((c8 ^ xi) * 8)];
        frag16 vf1 = *(const frag16*)&Vc[(32 + l31) * 64 + ((c8 ^ xi) * 8)];
        O0 = __builtin_amdgcn_mfma_f32_32x32x16_bf16(vf0, Pf[k2], O0, 0, 0, 0);
        O1 = __builtin_amdgcn_mfma_f32_32x32x16_bf16(vf1, Pf[k2], O1, 0, 0, 0);
    }
}

// ---------------- uniform split-K causal flash attention ----------------
__global__ __launch_bounds__(256, 2) void flash_mfma(
    const __hip_bfloat16* __restrict__ q, const __hip_bfloat16* __restrict__ k,
    const __hip_bfloat16* __restrict__ vT, __hip_bfloat16* __restrict__ y,
    float* __restrict__ Op, float* __restrict__ Lp)
{
    const int g = blockIdx.x;            // 512
    const int bh = g & 31;
    const int pr = g >> 5;
    const int qthalf = pr & 7;
    const int part = pr >> 3;
    const int qt_lo = qthalf, qt_hi = 15 - qthalf;
    const int nlo = 2 * qt_lo + 2;
    const int S = 17 - nlo;
    const int b = bh >> 4, h = bh & 15;
    const int tid = threadIdx.x;
    const int w = tid >> 6;
    const int lane = tid & 63;
    const int l31 = lane & 31;
    const int hi = lane >> 5;
    const int xi = l31 & 7;
    const int paddr = (lane ^ 32) << 2;

    __shared__ __align__(16) __hip_bfloat16 KsF[2][4096];
    __shared__ __align__(16) __hip_bfloat16 VsF[2][4096];

    const size_t base = (size_t)bh * TT * DHEAD;
    const __hip_bfloat16* qb = q + base;
    const __hip_bfloat16* kb = k + base;
    const __hip_bfloat16* vb = vT + base;

    const int ktd_lo = 2 * qt_lo + (w >> 1);
    const int ktd_hi = 2 * qt_hi + (w >> 1);
    const int qlane_lo = qt_lo * 128 + w * 32 + l31;
    const int qlane_hi = qt_hi * 128 + w * 32 + l31;

    const int k0off  = part ? S : 0;
    const int nsteps = part ? 17 : ((nlo > S) ? nlo : S);

    int offK[2], offV[2];
    #pragma unroll
    for (int j = 0; j < 2; j++) {
        int Lc = w * 128 + j * 64 + lane;
        int r = Lc >> 3, c8 = Lc & 7, g8 = c8 ^ (r & 7);
        offK[j] = r * 64 + g8 * 8;
        offV[j] = r * TT + g8 * 8;
    }

    frag16 qB_hi[4], qB_lo[4];
    #pragma unroll
    for (int kt4 = 0; kt4 < 4; kt4++)
        qB_hi[kt4] = *(const frag16*)&qb[(size_t)qlane_hi * DHEAD + kt4 * 16 + hi * 8];
    if (part == 0) {
        #pragma unroll
        for (int kt4 = 0; kt4 < 4; kt4++)
            qB_lo[kt4] = *(const frag16*)&qb[(size_t)qlane_lo * DHEAD + kt4 * 16 + hi * 8];
    }

    f32x16 Olo0 = {}, Olo1 = {}, Ohi0 = {}, Ohi1 = {};
    float l_lo = 0.0f, l_hi = 0.0f;

    #pragma unroll
    for (int j = 0; j < 2; j++) {
        __builtin_amdgcn_global_load_lds(AS1(kb + (size_t)k0off * 4096 + offK[j]),
                                         AS3(&KsF[0][w * 1024 + j * 512]), 16, 0, 0);
        __builtin_amdgcn_global_load_lds(AS1(vb + (size_t)k0off * 64 + offV[j]),
                                         AS3(&VsF[0][w * 1024 + j * 512]), 16, 0, 0);
    }

    for (int kt = 0; kt < nsteps; kt++) {
        const int cur = kt & 1;
        __syncthreads();
        if (kt + 1 < nsteps) {
            const int phys1 = k0off + kt + 1;
            #pragma unroll
            for (int j = 0; j < 2; j++) {
                __builtin_amdgcn_global_load_lds(AS1(kb + (size_t)phys1 * 4096 + offK[j]),
                                                 AS3(&KsF[cur ^ 1][w * 1024 + j * 512]), 16, 0, 0);
                __builtin_amdgcn_global_load_lds(AS1(vb + (size_t)phys1 * 64 + offV[j]),
                                                 AS3(&VsF[cur ^ 1][w * 1024 + j * 512]), 16, 0, 0);
            }
        }
        const __hip_bfloat16* Kc = KsF[cur];
        const __hip_bfloat16* Vc = VsF[cur];
        if (part == 0) {
            if (kt <= ktd_lo)
                attn_tile(Kc, Vc, qB_lo, Olo0, Olo1, l_lo, l31, hi, xi, paddr,
                          kt == ktd_lo, kt * 64, qlane_lo);
            if (kt < S)
                attn_tile(Kc, Vc, qB_hi, Ohi0, Ohi1, l_hi, l31, hi, xi, paddr,
                          false, 0, qlane_hi);
        } else {
            const int phys = S + kt;
            if (phys <= ktd_hi)
                attn_tile(Kc, Vc, qB_hi, Ohi0, Ohi1, l_hi, l31, hi, xi, paddr,
                          phys == ktd_hi, phys * 64, qlane_hi);
        }
    }

    if (part == 0) {
        float lother = __int_as_float(__builtin_amdgcn_ds_bpermute(paddr, __float_as_int(l_lo)));
        float inv = 1.0f / (l_lo + lother);
        float* o0 = (float*)&Olo0;
        float* o1 = (float*)&Olo1;
        __hip_bfloat16* yp = y + ((size_t)(b * TT + qlane_lo)) * DDim + h * DHEAD;
        #pragma unroll
        for (int gg = 0; gg < 4; gg++) {
            int d0 = 8 * gg + 4 * hi;
            uint2 pa, pb;
            pa.x = pk2(o0[4*gg+0] * inv, o0[4*gg+1] * inv);
            pa.y = pk2(o0[4*gg+2] * inv, o0[4*gg+3] * inv);
            pb.x = pk2(o1[4*gg+0] * inv, o1[4*gg+1] * inv);
            pb.y = pk2(o1[4*gg+2] * inv, o1[4*gg+3] * inv);
            *(uint2*)&yp[d0] = pa;
            *(uint2*)&yp[32 + d0] = pb;
        }
    }
    {
        float lother = __int_as_float(__builtin_amdgcn_ds_bpermute(paddr, __float_as_int(l_hi)));
        float ltot = l_hi + lother;
        const int slot = bh * 8 + qthalf;
        const int rloc = w * 32 + l31;
        float* Od = Op + ((size_t)part * 256 + slot) * 8192 + (size_t)rloc * 64;
        float* o0 = (float*)&Ohi0;
        float* o1 = (float*)&Ohi1;
        #pragma unroll
        for (int gg = 0; gg < 4; gg++) {
            int d0 = 8 * gg + 4 * hi;
            *(float4*)&Od[d0]      = (float4){o0[4*gg+0], o0[4*gg+1], o0[4*gg+2], o0[4*gg+3]};
            *(float4*)&Od[32 + d0] = (float4){o1[4*gg+0], o1[4*gg+1], o1[4*gg+2], o1[4*gg+3]};
        }
        if (hi == 0) Lp[part * 32768 + slot * 128 + rloc] = ltot;
    }
}

extern "C" void kernel_launch(void* const* d_in, const int* in_sizes, int n_in,
                              void* d_out, int out_size, void* d_ws, size_t ws_size,
                              hipStream_t stream) {
    const float* x      = (const float*)d_in[0];
    const float* W_abq  = (const float*)d_in[1];
    const float* W_abkv = (const float*)d_in[2];
    const float* W_o    = (const float*)d_in[3];
    float* out = (float*)d_out;

    char* ws = (char*)d_ws;
    float* abqkv = (float*)ws;                   ws += (size_t)4096 * NQK * 4;
    __hip_bfloat16* qb = (__hip_bfloat16*)ws;    ws += (size_t)4194304 * 2;
    __hip_bfloat16* kb = (__hip_bfloat16*)ws;    ws += (size_t)4194304 * 2;
    __hip_bfloat16* vT = (__hip_bfloat16*)ws;    ws += (size_t)4194304 * 2;
    __hip_bfloat16* yb = (__hip_bfloat16*)ws;    ws += (size_t)4194304 * 2;
    float* Op = (float*)ws;                      ws += (size_t)2 * 2097152 * 4;
    float* Lp = (float*)ws;                      ws += (size_t)2 * 32768 * 4;

    gemm_proj<<<dim3(7, 32), dim3(256), 0, stream>>>(x, W_abq, W_abkv, abqkv);
    qkv_kernel<<<dim3(1024), dim3(256), 0, stream>>>(abqkv, qb, kb, vT);
    flash_mfma<<<dim3(512), dim3(256), 0, stream>>>(qb, kb, vT, yb, Op, Lp);
    gemm_out<<<dim3(8, 32), dim3(256), 0, stream>>>(yb, Op, Lp, W_o, out);
}

// Round 9
// 176.720 us; speedup vs baseline: 1.1677x; 1.1677x over previous
//
#include <hip/hip_runtime.h>
#include <hip/hip_bf16.h>
#include <math.h>

#define NHEADS 16
#define DHEAD  64
#define CHDIM  80
#define RQn    6
#define RKn    2
#define RVn    2
#define BB     2
#define TT     2048
#define DDim   1024
#define NQK    800   // 480 + 320 combined projection rows

using frag16 = __attribute__((ext_vector_type(8))) short;   // 8 bf16 (4 VGPR)
using f32x4  = __attribute__((ext_vector_type(4))) float;   // 4 fp32 acc
using f32x16 = __attribute__((ext_vector_type(16))) float;  // 32x32 acc

#define AS1(p) ((const __attribute__((address_space(1))) unsigned int*)(p))
#define AS3(p) ((__attribute__((address_space(3))) unsigned int*)(p))

static __device__ __forceinline__ unsigned short bf16_bits(float f) {
    __hip_bfloat16 h = __float2bfloat16(f);
    return *(unsigned short*)&h;
}
static __device__ __forceinline__ unsigned int pk2(float a, float b) {
    return ((unsigned int)bf16_bits(b) << 16) | (unsigned int)bf16_bits(a);
}

// ---------------- fused fp32 -> bf16 convert (4 segments, 1 launch) ----------
__global__ __launch_bounds__(256) void cvt_all(
    const float* __restrict__ x, const float* __restrict__ wq,
    const float* __restrict__ wk, const float* __restrict__ wo,
    __hip_bfloat16* __restrict__ xb, __hip_bfloat16* __restrict__ wqk,
    __hip_bfloat16* __restrict__ wob)
{
    int bid = blockIdx.x;
    const float* src; __hip_bfloat16* dst; int n4;
    if (bid < 4096)      { src = x;  dst = xb;            n4 = 1048576; }
    else if (bid < 4576) { bid -= 4096; src = wq; dst = wqk;           n4 = 122880; }
    else if (bid < 4896) { bid -= 4576; src = wk; dst = wqk + 491520;  n4 = 81920; }
    else                 { bid -= 4896; src = wo; dst = wob;           n4 = 262144; }
    int i = bid * 256 + threadIdx.x;
    if (i < n4) {
        float4 v = *(const float4*)&src[i * 4];
        ushort4 o;
        o.x = bf16_bits(v.x); o.y = bf16_bits(v.y);
        o.z = bf16_bits(v.z); o.w = bf16_bits(v.w);
        *(ushort4*)&dst[i * 4] = o;
    }
}

// ---------- GEMM: C[M,N] = A[M,K]_bf16 * W[N,K]_bf16^T, 64x128 tile ---------
// 2 blocks/CU (vs 1 at 128x128): cross-block overlap hides the barrier drain.
// Wave w: rows 0..63 (mt 0..3), cols w*32 (nt 0..1). Dbuf global_load_lds.
__global__ __launch_bounds__(256) void gemm_bf16(
    const __hip_bfloat16* __restrict__ A, const __hip_bfloat16* __restrict__ W,
    float* __restrict__ C, int M, int N, int K)
{
    __shared__ __hip_bfloat16 Asl[2][64 * 64];
    __shared__ __hip_bfloat16 Bsl[2][128 * 64];
    const int tid = threadIdx.x;
    const int w = tid >> 6, lane = tid & 63;
    const int l16 = lane & 15, quad = lane >> 4;
    const int bm = blockIdx.y * 64, bn = blockIdx.x * 128;

    // staging geometry
    int rSA[2], cSA[2];
    #pragma unroll
    for (int j = 0; j < 2; j++) {
        int L = (w * 2 + j) * 64 + lane;
        rSA[j] = L >> 3;
        cSA[j] = (L & 7) ^ (rSA[j] & 7);
    }
    int rSB[4], cSB[4];
    #pragma unroll
    for (int j = 0; j < 4; j++) {
        int L = (w * 4 + j) * 64 + lane;
        int r = L >> 3;
        cSB[j] = (L & 7) ^ (r & 7);
        int rb = bn + r;
        rSB[j] = (rb < N) ? rb : (N - 1);
    }

    f32x4 acc[4][2];
    #pragma unroll
    for (int mt = 0; mt < 4; mt++)
        #pragma unroll
        for (int nt = 0; nt < 2; nt++)
            acc[mt][nt] = (f32x4){0.f, 0.f, 0.f, 0.f};

    const int nK = K >> 6;
    #pragma unroll
    for (int j = 0; j < 2; j++)
        __builtin_amdgcn_global_load_lds(AS1(A + (size_t)(bm + rSA[j]) * K + cSA[j] * 8),
                                         AS3(&Asl[0][(w * 2 + j) * 512]), 16, 0, 0);
    #pragma unroll
    for (int j = 0; j < 4; j++)
        __builtin_amdgcn_global_load_lds(AS1(W + (size_t)rSB[j] * K + cSB[j] * 8),
                                         AS3(&Bsl[0][(w * 4 + j) * 512]), 16, 0, 0);

    for (int kk = 0; kk < nK; kk++) {
        const int cur = kk & 1;
        __syncthreads();
        if (kk + 1 < nK) {
            const int k1 = (kk + 1) * 64;
            #pragma unroll
            for (int j = 0; j < 2; j++)
                __builtin_amdgcn_global_load_lds(AS1(A + (size_t)(bm + rSA[j]) * K + k1 + cSA[j] * 8),
                                                 AS3(&Asl[cur ^ 1][(w * 2 + j) * 512]), 16, 0, 0);
            #pragma unroll
            for (int j = 0; j < 4; j++)
                __builtin_amdgcn_global_load_lds(AS1(W + (size_t)rSB[j] * K + k1 + cSB[j] * 8),
                                                 AS3(&Bsl[cur ^ 1][(w * 4 + j) * 512]), 16, 0, 0);
        }
        #pragma unroll
        for (int ks = 0; ks < 2; ks++) {
            frag16 af[4], bf[2];
            #pragma unroll
            for (int mt = 0; mt < 4; mt++) {
                int r = mt * 16 + l16;
                af[mt] = *(const frag16*)&Asl[cur][r * 64 + (((ks * 4 + quad) ^ (r & 7)) * 8)];
            }
            #pragma unroll
            for (int nt = 0; nt < 2; nt++) {
                int r = w * 32 + nt * 16 + l16;
                bf[nt] = *(const frag16*)&Bsl[cur][r * 64 + (((ks * 4 + quad) ^ (r & 7)) * 8)];
            }
            #pragma unroll
            for (int mt = 0; mt < 4; mt++)
                #pragma unroll
                for (int nt = 0; nt < 2; nt++)
                    acc[mt][nt] = __builtin_amdgcn_mfma_f32_16x16x32_bf16(af[mt], bf[nt], acc[mt][nt], 0, 0, 0);
        }
    }
    #pragma unroll
    for (int mt = 0; mt < 4; mt++) {
        #pragma unroll
        for (int reg = 0; reg < 4; reg++) {
            int row = bm + mt * 16 + quad * 4 + reg;
            #pragma unroll
            for (int nt = 0; nt < 2; nt++) {
                int col = bn + w * 32 + nt * 16 + l16;
                if (col < N) C[(size_t)row * N + col] = acc[mt][nt][reg];
            }
        }
    }
}

// ---------------- RoPE + rank contraction, 4 tokens/block ----------
__global__ __launch_bounds__(256) void qkv_kernel(
    const float* __restrict__ ab,
    __hip_bfloat16* __restrict__ q, __hip_bfloat16* __restrict__ k,
    __hip_bfloat16* __restrict__ vT)
{
    const int tok0 = blockIdx.x * 4;
    const int w = threadIdx.x >> 6;
    const int d = threadIdx.x & 63;
    const int token = tok0 + w;
    const int b = token / TT;
    const int t = token % TT;
    __shared__ float sq[4][RQn * CHDIM];
    __shared__ float skv[4][(RKn + RVn) * CHDIM];
    __shared__ __align__(8) __hip_bfloat16 vbuf[NHEADS][DHEAD][4];
    const float* aq  = ab + (size_t)token * NQK;
    const float* akv = aq + 480;
    for (int i = d; i < RQn * CHDIM; i += 64) sq[w][i] = aq[i];
    for (int i = d; i < (RKn + RVn) * CHDIM; i += 64) skv[w][i] = akv[i];
    const int i32 = d & 31;
    float inv_freq = powf(10000.0f, -(float)i32 / 32.0f);
    float fr = (float)t * inv_freq;
    float c = cosf(fr), s = sinf(fr);
    float rot[4];
    #pragma unroll
    for (int r = 0; r < 4; r++) {
        float x1 = skv[w][r * CHDIM + NHEADS + i32];
        float x2 = skv[w][r * CHDIM + NHEADS + 32 + i32];
        rot[r] = (d < 32) ? (x1 * c + x2 * s) : (-x1 * s + x2 * c);
    }
    float bqv[RQn];
    #pragma unroll
    for (int r = 0; r < RQn; r++) bqv[r] = sq[w][r * CHDIM + NHEADS + d];
    #pragma unroll
    for (int h = 0; h < NHEADS; h++) {
        float accq = 0.0f;
        #pragma unroll
        for (int r = 0; r < RQn; r++)
            accq += sq[w][r * CHDIM + h] * bqv[r];
        q[((size_t)(b * NHEADS + h) * TT + t) * DHEAD + d] = __float2bfloat16(accq * (0.125f / 6.0f));
        float acck = 0.0f, accv = 0.0f;
        #pragma unroll
        for (int r = 0; r < RKn; r++)
            acck += skv[w][r * CHDIM + h] * rot[r];
        #pragma unroll
        for (int r = 0; r < RVn; r++)
            accv += skv[w][(RKn + r) * CHDIM + h] * rot[RKn + r];
        k[((size_t)(b * NHEADS + h) * TT + t) * DHEAD + d] = __float2bfloat16(acck * 0.5f);
        vbuf[h][d][w] = __float2bfloat16(accv * 0.5f);
    }
    __syncthreads();
    const int t0 = tok0 % TT;
    const int b0 = tok0 / TT;
    for (int row = threadIdx.x; row < NHEADS * DHEAD; row += 256) {
        int h = row >> 6, dd = row & 63;
        *(uint2*)&vT[((size_t)(b0 * NHEADS + h) * DHEAD + dd) * TT + t0] =
            *(const uint2*)&vbuf[h][dd][0];
    }
}

// -------- P^T B-frag construction from exp'd S registers (shared helper) ----
static __device__ __forceinline__ void build_pfrag(
    const float* s0, const float* s1, frag16 Pf[4], const int hi, const int paddr)
{
    #pragma unroll
    for (int k2 = 0; k2 < 4; k2++) {
        const float* sF = (k2 >= 2) ? s1 : s0;
        const int bs = 8 * (k2 & 1);
        unsigned int u0a = pk2(sF[bs + 0], sF[bs + 1]);
        unsigned int u0b = pk2(sF[bs + 2], sF[bs + 3]);
        unsigned int u1a = pk2(sF[bs + 4], sF[bs + 5]);
        unsigned int u1b = pk2(sF[bs + 6], sF[bs + 7]);
        unsigned int r0a = (unsigned int)__builtin_amdgcn_ds_bpermute(paddr, (int)u0a);
        unsigned int r0b = (unsigned int)__builtin_amdgcn_ds_bpermute(paddr, (int)u0b);
        unsigned int r1a = (unsigned int)__builtin_amdgcn_ds_bpermute(paddr, (int)u1a);
        unsigned int r1b = (unsigned int)__builtin_amdgcn_ds_bpermute(paddr, (int)u1b);
        union { frag16 f; unsigned int u[4]; } pf;
        pf.u[0] = hi ? r1a : u0a;
        pf.u[1] = hi ? r1b : u0b;
        pf.u[2] = hi ? u1a : r0a;
        pf.u[3] = hi ? u1b : r0b;
        Pf[k2] = pf.f;
    }
}

// ---------------- single attention tile ----------------
static __device__ __forceinline__ void attn_tile(
    const __hip_bfloat16* __restrict__ Kc, const __hip_bfloat16* __restrict__ Vc,
    const frag16 qB[4], f32x16& O0, f32x16& O1, float& lpart,
    const int l31, const int hi, const int xi, const int paddr,
    const bool domask, const int kb0, const int qlane)
{
    f32x16 ST0 = {}, ST1 = {};
    #pragma unroll
    for (int kt4 = 0; kt4 < 4; kt4++) {
        int c8 = kt4 * 2 + hi;
        frag16 kf0 = *(const frag16*)&Kc[l31 * 64 + ((c8 ^ xi) * 8)];
        frag16 kf1 = *(const frag16*)&Kc[(32 + l31) * 64 + ((c8 ^ xi) * 8)];
        ST0 = __builtin_amdgcn_mfma_f32_32x32x16_bf16(kf0, qB[kt4], ST0, 0, 0, 0);
        ST1 = __builtin_amdgcn_mfma_f32_32x32x16_bf16(kf1, qB[kt4], ST1, 0, 0, 0);
    }
    float* s0 = (float*)&ST0;
    float* s1 = (float*)&ST1;
    if (domask) {
        int kbq = kb0 + 4 * hi;
        #pragma unroll
        for (int reg = 0; reg < 16; reg++) {
            int rowc = (reg & 3) + 8 * (reg >> 2);
            if (kbq + rowc > qlane)      s0[reg] = -1e30f;
            if (kbq + 32 + rowc > qlane) s1[reg] = -1e30f;
        }
    }
    #pragma unroll
    for (int reg = 0; reg < 16; reg++) {
        float p0 = __expf(s0[reg]);
        float p1 = __expf(s1[reg]);
        s0[reg] = p0; s1[reg] = p1;
        lpart += p0 + p1;
    }
    frag16 Pf[4];
    build_pfrag(s0, s1, Pf, hi, paddr);
    #pragma unroll
    for (int k2 = 0; k2 < 4; k2++) {
        int c8 = k2 * 2 + hi;
        frag16 vf0 = *(const frag16*)&Vc[l31 * 64 + ((c8 ^ xi) * 8)];
        frag16 vf1 = *(const frag16*)&Vc[(32 + l31) * 64 + ((c8 ^ xi) * 8)];
        O0 = __builtin_amdgcn_mfma_f32_32x32x16_bf16(vf0, Pf[k2], O0, 0, 0, 0);
        O1 = __builtin_amdgcn_mfma_f32_32x32x16_bf16(vf1, Pf[k2], O1, 0, 0, 0);
    }
}

// ------- dual attention tile: lo+hi share K/V LDS reads, 2 indep chains -----
static __device__ __forceinline__ void attn_tile2(
    const __hip_bfloat16* __restrict__ Kc, const __hip_bfloat16* __restrict__ Vc,
    const frag16 qBlo[4], const frag16 qBhi[4],
    f32x16& Olo0, f32x16& Olo1, float& l_lo,
    f32x16& Ohi0, f32x16& Ohi1, float& l_hi,
    const int l31, const int hi, const int xi, const int paddr,
    const bool domask_lo, const int kb0, const int qlane_lo)
{
    f32x16 SL0 = {}, SL1 = {}, SH0 = {}, SH1 = {};
    #pragma unroll
    for (int kt4 = 0; kt4 < 4; kt4++) {
        int c8 = kt4 * 2 + hi;
        frag16 kf0 = *(const frag16*)&Kc[l31 * 64 + ((c8 ^ xi) * 8)];
        frag16 kf1 = *(const frag16*)&Kc[(32 + l31) * 64 + ((c8 ^ xi) * 8)];
        SL0 = __builtin_amdgcn_mfma_f32_32x32x16_bf16(kf0, qBlo[kt4], SL0, 0, 0, 0);
        SH0 = __builtin_amdgcn_mfma_f32_32x32x16_bf16(kf0, qBhi[kt4], SH0, 0, 0, 0);
        SL1 = __builtin_amdgcn_mfma_f32_32x32x16_bf16(kf1, qBlo[kt4], SL1, 0, 0, 0);
        SH1 = __builtin_amdgcn_mfma_f32_32x32x16_bf16(kf1, qBhi[kt4], SH1, 0, 0, 0);
    }
    float* sl0 = (float*)&SL0; float* sl1 = (float*)&SL1;
    float* sh0 = (float*)&SH0; float* sh1 = (float*)&SH1;
    if (domask_lo) {
        int kbq = kb0 + 4 * hi;
        #pragma unroll
        for (int reg = 0; reg < 16; reg++) {
            int rowc = (reg & 3) + 8 * (reg >> 2);
            if (kbq + rowc > qlane_lo)      sl0[reg] = -1e30f;
            if (kbq + 32 + rowc > qlane_lo) sl1[reg] = -1e30f;
        }
    }
    #pragma unroll
    for (int reg = 0; reg < 16; reg++) {
        float a = __expf(sl0[reg]); float b = __expf(sl1[reg]);
        float c = __expf(sh0[reg]); float d = __expf(sh1[reg]);
        sl0[reg] = a; sl1[reg] = b; sh0[reg] = c; sh1[reg] = d;
        l_lo += a + b; l_hi += c + d;
    }
    frag16 PfL[4], PfH[4];
    build_pfrag(sl0, sl1, PfL, hi, paddr);
    build_pfrag(sh0, sh1, PfH, hi, paddr);
    #pragma unroll
    for (int k2 = 0; k2 < 4; k2++) {
        int c8 = k2 * 2 + hi;
        frag16 vf0 = *(const frag16*)&Vc[l31 * 64 + ((c8 ^ xi) * 8)];
        frag16 vf1 = *(const frag16*)&Vc[(32 + l31) * 64 + ((c8 ^ xi) * 8)];
        Olo0 = __builtin_amdgcn_mfma_f32_32x32x16_bf16(vf0, PfL[k2], Olo0, 0, 0, 0);
        Ohi0 = __builtin_amdgcn_mfma_f32_32x32x16_bf16(vf0, PfH[k2], Ohi0, 0, 0, 0);
        Olo1 = __builtin_amdgcn_mfma_f32_32x32x16_bf16(vf1, PfL[k2], Olo1, 0, 0, 0);
        Ohi1 = __builtin_amdgcn_mfma_f32_32x32x16_bf16(vf1, PfH[k2], Ohi1, 0, 0, 0);
    }
}

// ---------------- uniform split-K causal flash attention ----------------
__global__ __launch_bounds__(256, 2) void flash_mfma(
    const __hip_bfloat16* __restrict__ q, const __hip_bfloat16* __restrict__ k,
    const __hip_bfloat16* __restrict__ vT, __hip_bfloat16* __restrict__ y,
    float* __restrict__ Op, float* __restrict__ Lp)
{
    const int g = blockIdx.x;            // 512
    const int bh = g & 31;
    const int pr = g >> 5;
    const int qthalf = pr & 7;
    const int part = pr >> 3;
    const int qt_lo = qthalf, qt_hi = 15 - qthalf;
    const int nlo = 2 * qt_lo + 2;
    const int S = 17 - nlo;
    const int b = bh >> 4, h = bh & 15;
    const int tid = threadIdx.x;
    const int w = tid >> 6;
    const int lane = tid & 63;
    const int l31 = lane & 31;
    const int hi = lane >> 5;
    const int xi = l31 & 7;
    const int paddr = (lane ^ 32) << 2;

    __shared__ __align__(16) __hip_bfloat16 KsF[2][4096];
    __shared__ __align__(16) __hip_bfloat16 VsF[2][4096];

    const size_t base = (size_t)bh * TT * DHEAD;
    const __hip_bfloat16* qb = q + base;
    const __hip_bfloat16* kb = k + base;
    const __hip_bfloat16* vb = vT + base;

    const int ktd_lo = 2 * qt_lo + (w >> 1);
    const int ktd_hi = 2 * qt_hi + (w >> 1);
    const int qlane_lo = qt_lo * 128 + w * 32 + l31;
    const int qlane_hi = qt_hi * 128 + w * 32 + l31;

    const int k0off  = part ? S : 0;
    const int nsteps = part ? 17 : ((nlo > S) ? nlo : S);

    int offK[2], offV[2];
    #pragma unroll
    for (int j = 0; j < 2; j++) {
        int Lc = w * 128 + j * 64 + lane;
        int r = Lc >> 3, c8 = Lc & 7, g8 = c8 ^ (r & 7);
        offK[j] = r * 64 + g8 * 8;
        offV[j] = r * TT + g8 * 8;
    }

    frag16 qB_hi[4], qB_lo[4];
    #pragma unroll
    for (int kt4 = 0; kt4 < 4; kt4++)
        qB_hi[kt4] = *(const frag16*)&qb[(size_t)qlane_hi * DHEAD + kt4 * 16 + hi * 8];
    if (part == 0) {
        #pragma unroll
        for (int kt4 = 0; kt4 < 4; kt4++)
            qB_lo[kt4] = *(const frag16*)&qb[(size_t)qlane_lo * DHEAD + kt4 * 16 + hi * 8];
    }

    f32x16 Olo0 = {}, Olo1 = {}, Ohi0 = {}, Ohi1 = {};
    float l_lo = 0.0f, l_hi = 0.0f;

    #pragma unroll
    for (int j = 0; j < 2; j++) {
        __builtin_amdgcn_global_load_lds(AS1(kb + (size_t)k0off * 4096 + offK[j]),
                                         AS3(&KsF[0][w * 1024 + j * 512]), 16, 0, 0);
        __builtin_amdgcn_global_load_lds(AS1(vb + (size_t)k0off * 64 + offV[j]),
                                         AS3(&VsF[0][w * 1024 + j * 512]), 16, 0, 0);
    }

    for (int kt = 0; kt < nsteps; kt++) {
        const int cur = kt & 1;
        __syncthreads();
        if (kt + 1 < nsteps) {
            const int phys1 = k0off + kt + 1;
            #pragma unroll
            for (int j = 0; j < 2; j++) {
                __builtin_amdgcn_global_load_lds(AS1(kb + (size_t)phys1 * 4096 + offK[j]),
                                                 AS3(&KsF[cur ^ 1][w * 1024 + j * 512]), 16, 0, 0);
                __builtin_amdgcn_global_load_lds(AS1(vb + (size_t)phys1 * 64 + offV[j]),
                                                 AS3(&VsF[cur ^ 1][w * 1024 + j * 512]), 16, 0, 0);
            }
        }
        const __hip_bfloat16* Kc = KsF[cur];
        const __hip_bfloat16* Vc = VsF[cur];
        if (part == 0) {
            const bool do_lo = (kt <= ktd_lo);
            const bool do_hi = (kt < S);
            if (do_lo && do_hi)
                attn_tile2(Kc, Vc, qB_lo, qB_hi, Olo0, Olo1, l_lo, Ohi0, Ohi1, l_hi,
                           l31, hi, xi, paddr, kt == ktd_lo, kt * 64, qlane_lo);
            else if (do_lo)
                attn_tile(Kc, Vc, qB_lo, Olo0, Olo1, l_lo, l31, hi, xi, paddr,
                          kt == ktd_lo, kt * 64, qlane_lo);
            else if (do_hi)
                attn_tile(Kc, Vc, qB_hi, Ohi0, Ohi1, l_hi, l31, hi, xi, paddr,
                          false, 0, qlane_hi);
        } else {
            const int phys = S + kt;
            if (phys <= ktd_hi)
                attn_tile(Kc, Vc, qB_hi, Ohi0, Ohi1, l_hi, l31, hi, xi, paddr,
                          phys == ktd_hi, phys * 64, qlane_hi);
        }
    }

    if (part == 0) {
        float lother = __int_as_float(__builtin_amdgcn_ds_bpermute(paddr, __float_as_int(l_lo)));
        float inv = 1.0f / (l_lo + lother);
        float* o0 = (float*)&Olo0;
        float* o1 = (float*)&Olo1;
        __hip_bfloat16* yp = y + ((size_t)(b * TT + qlane_lo)) * DDim + h * DHEAD;
        #pragma unroll
        for (int gg = 0; gg < 4; gg++) {
            int d0 = 8 * gg + 4 * hi;
            uint2 pa, pb;
            pa.x = pk2(o0[4*gg+0] * inv, o0[4*gg+1] * inv);
            pa.y = pk2(o0[4*gg+2] * inv, o0[4*gg+3] * inv);
            pb.x = pk2(o1[4*gg+0] * inv, o1[4*gg+1] * inv);
            pb.y = pk2(o1[4*gg+2] * inv, o1[4*gg+3] * inv);
            *(uint2*)&yp[d0] = pa;
            *(uint2*)&yp[32 + d0] = pb;
        }
    }
    {
        float lother = __int_as_float(__builtin_amdgcn_ds_bpermute(paddr, __float_as_int(l_hi)));
        float ltot = l_hi + lother;
        const int slot = bh * 8 + qthalf;
        const int rloc = w * 32 + l31;
        float* Od = Op + ((size_t)part * 256 + slot) * 8192 + (size_t)rloc * 64;
        float* o0 = (float*)&Ohi0;
        float* o1 = (float*)&Ohi1;
        #pragma unroll
        for (int gg = 0; gg < 4; gg++) {
            int d0 = 8 * gg + 4 * hi;
            *(float4*)&Od[d0]      = (float4){o0[4*gg+0], o0[4*gg+1], o0[4*gg+2], o0[4*gg+3]};
            *(float4*)&Od[32 + d0] = (float4){o1[4*gg+0], o1[4*gg+1], o1[4*gg+2], o1[4*gg+3]};
        }
        if (hi == 0) Lp[part * 32768 + slot * 128 + rloc] = ltot;
    }
}

// ---------------- combine the two hi-partials, normalize, write y -----------
__global__ __launch_bounds__(256) void combine(
    const float* __restrict__ Op, const float* __restrict__ Lp,
    __hip_bfloat16* __restrict__ y)
{
    int idx = blockIdx.x * 256 + threadIdx.x;   // 0..32767 (slot-rows)
    int slot = idx >> 7, row = idx & 127;
    int bh = slot >> 3, qthalf = slot & 7;
    int b = bh >> 4, h = bh & 15;
    int qrow = (15 - qthalf) * 128 + row;
    float l0 = Lp[slot * 128 + row];
    float l1 = Lp[32768 + slot * 128 + row];
    float inv = 1.0f / (l0 + l1);
    const float* p0 = Op + (size_t)(slot * 128 + row) * 64;
    const float* p1 = p0 + 2097152;
    __hip_bfloat16* yp = y + ((size_t)(b * TT + qrow)) * DDim + h * DHEAD;
    #pragma unroll
    for (int c = 0; c < 64; c += 8) {
        float4 a0 = *(const float4*)&p0[c];
        float4 a1 = *(const float4*)&p0[c + 4];
        float4 b0 = *(const float4*)&p1[c];
        float4 b1 = *(const float4*)&p1[c + 4];
        uint4 o;
        o.x = pk2((a0.x + b0.x) * inv, (a0.y + b0.y) * inv);
        o.y = pk2((a0.z + b0.z) * inv, (a0.w + b0.w) * inv);
        o.z = pk2((a1.x + b1.x) * inv, (a1.y + b1.y) * inv);
        o.w = pk2((a1.z + b1.z) * inv, (a1.w + b1.w) * inv);
        *(uint4*)&yp[c] = o;
    }
}

extern "C" void kernel_launch(void* const* d_in, const int* in_sizes, int n_in,
                              void* d_out, int out_size, void* d_ws, size_t ws_size,
                              hipStream_t stream) {
    const float* x      = (const float*)d_in[0];
    const float* W_abq  = (const float*)d_in[1];
    const float* W_abkv = (const float*)d_in[2];
    const float* W_o    = (const float*)d_in[3];
    float* out = (float*)d_out;

    char* ws = (char*)d_ws;
    __hip_bfloat16* xb   = (__hip_bfloat16*)ws;  ws += (size_t)4194304 * 2;
    __hip_bfloat16* wqk  = (__hip_bfloat16*)ws;  ws += (size_t)NQK * 1024 * 2;
    __hip_bfloat16* wo_b = (__hip_bfloat16*)ws;  ws += (size_t)1048576 * 2;
    float* abqkv = (float*)ws;                   ws += (size_t)4096 * NQK * 4;
    __hip_bfloat16* qb = (__hip_bfloat16*)ws;    ws += (size_t)4194304 * 2;
    __hip_bfloat16* kb = (__hip_bfloat16*)ws;    ws += (size_t)4194304 * 2;
    __hip_bfloat16* vT = (__hip_bfloat16*)ws;    ws += (size_t)4194304 * 2;
    __hip_bfloat16* yb = (__hip_bfloat16*)ws;    ws += (size_t)4194304 * 2;
    float* Op = (float*)ws;                      ws += (size_t)2 * 2097152 * 4;
    float* Lp = (float*)ws;                      ws += (size_t)2 * 32768 * 4;

    cvt_all<<<dim3(5920), dim3(256), 0, stream>>>(x, W_abq, W_abkv, W_o, xb, wqk, wo_b);
    gemm_bf16<<<dim3(7, 64), dim3(256), 0, stream>>>(xb, wqk, abqkv, 4096, NQK, 1024);
    qkv_kernel<<<dim3(1024), dim3(256), 0, stream>>>(abqkv, qb, kb, vT);
    flash_mfma<<<dim3(512), dim3(256), 0, stream>>>(qb, kb, vT, yb, Op, Lp);
    combine<<<dim3(128), dim3(256), 0, stream>>>(Op, Lp, yb);
    gemm_bf16<<<dim3(8, 64), dim3(256), 0, stream>>>(yb, wo_b, out, 4096, 1024, 1024);
}